// Round 1
// baseline (274.577 us; speedup 1.0000x reference)
//
#include <hip/hip_runtime.h>

#define NN 100000
#define NE 220000
#define HD 128
#define NG 4096
#define NPE 5
#define NB_SCAN ((NN + 255) / 256)   // 391
#define NBX4 ((NN * HD / 4) / 256)   // 12500 (exact)
#define NBW 128                      // prep_w blocks
#define NBD ((2 * NE + 255) / 256)   // 1719
#define NBAG ((NN + 63) / 64)        // 1563 agg+gemm blocks per branch
#define LDP 136

typedef unsigned int uint;
typedef unsigned short ushort;
typedef __attribute__((ext_vector_type(8))) short bf16x8;
typedef __attribute__((ext_vector_type(4))) float f32x4;

__device__ __forceinline__ float bf2f(uint u16) {
    return __uint_as_float(u16 << 16);
}
__device__ __forceinline__ ushort f2bf(float f) {
    uint u = __float_as_uint(f);
    u += 0x7fffu + ((u >> 16) & 1u);   // RNE
    return (ushort)(u >> 16);
}

// Fused front: [0,NBX4) compute x/xb (4 feats/thread); then Wcat; then degree.
__global__ void k_front(const int* __restrict__ tok, const float* __restrict__ pe,
                        const float* __restrict__ embed, const float* __restrict__ Wtr,
                        const float* __restrict__ bt,
                        float* __restrict__ x, ushort* __restrict__ xb,
                        const float* __restrict__ W1, const float* __restrict__ Wv1,
                        ushort* __restrict__ Wcat,
                        const int* __restrict__ ei, const int* __restrict__ vei,
                        int* __restrict__ cnt) {
    int b = blockIdx.x;
    if (b < NBX4) {
        int idx = b * 256 + threadIdx.x;        // one float4 of x
        int n = idx >> 5, q = idx & 31;
        int t = tok[n];
        float4 acc = ((const float4*)(embed + (size_t)t * HD))[q];
        float4 bv = ((const float4*)bt)[q];
        acc.x += bv.x; acc.y += bv.y; acc.z += bv.z; acc.w += bv.w;
        const float* pen = pe + n * NPE;
#pragma unroll
        for (int k = 0; k < NPE; ++k) {
            float p = pen[k];
            float4 wv = ((const float4*)(Wtr + k * HD))[q];
            acc.x += p * wv.x; acc.y += p * wv.y;
            acc.z += p * wv.z; acc.w += p * wv.w;
        }
        ((float4*)x)[idx] = acc;
        uint2 pk;
        pk.x = (uint)f2bf(acc.x) | ((uint)f2bf(acc.y) << 16);
        pk.y = (uint)f2bf(acc.z) | ((uint)f2bf(acc.w) << 16);
        ((uint2*)xb)[idx] = pk;
    } else if (b < NBX4 + NBW) {
        int t = (b - NBX4) * 256 + threadIdx.x;   // 32768
        int f = t >> 7, k = t & 127;
        const float* W = (f < HD) ? W1 : Wv1;
        Wcat[t] = f2bf(W[k * HD + (f & 127)]);    // Wcat[f][k] = W[k][f]
    } else {
        int t = (b - NBX4 - NBW) * 256 + threadIdx.x;
        if (t < 2 * NE) {
            int br = t >= NE;
            int e = t - br * NE;
            const int* S = br ? vei : ei;
            atomicAdd(&cnt[br * NN + S[NE + e]], 1);
        }
    }
}

// per-block exclusive scan + dinv
__global__ void k_scan1(const int* __restrict__ cnt, int* __restrict__ off,
                        int* __restrict__ bsum, float* __restrict__ dinv) {
    __shared__ int s[256];
    int br = blockIdx.x / NB_SCAN;
    int blk = blockIdx.x % NB_SCAN;
    int tid = threadIdx.x;
    int i = blk * 256 + tid;
    int v = (i < NN) ? cnt[br * NN + i] : 0;
    if (i < NN) dinv[br * NN + i] = rsqrtf((float)v + 1.0f);
    s[tid] = v;
    __syncthreads();
    for (int d = 1; d < 256; d <<= 1) {
        int t = (tid >= d) ? s[tid - d] : 0;
        __syncthreads();
        s[tid] += t;
        __syncthreads();
    }
    if (i < NN) off[br * NN + i] = s[tid] - v;
    if (tid == 255) bsum[br * 512 + blk] = s[255];
}

__global__ void k_scan2(int* __restrict__ bsum) {
    __shared__ int s[512];
    int br = blockIdx.x;
    int tid = threadIdx.x;
    int v = (tid < NB_SCAN) ? bsum[br * 512 + tid] : 0;
    s[tid] = v;
    __syncthreads();
    for (int d = 1; d < 512; d <<= 1) {
        int t = (tid >= d) ? s[tid - d] : 0;
        __syncthreads();
        s[tid] += t;
        __syncthreads();
    }
    if (tid < NB_SCAN) bsum[br * 512 + tid] = s[tid] - v;
}

__global__ void k_scan3(int* __restrict__ off, const int* __restrict__ bsum,
                        int* __restrict__ cur) {
    int br = blockIdx.x / NB_SCAN;
    int blk = blockIdx.x % NB_SCAN;
    int i = blk * 256 + threadIdx.x;
    if (i < NN) {
        int o = off[br * NN + i] + bsum[br * 512 + blk];
        off[br * NN + i] = o;
        cur[br * NN + i] = o;
    }
}

// Scatter packed edge record {src, coef} — one 8B store per edge.
__global__ void k_scatter(const int* __restrict__ ei, const int* __restrict__ vei,
                          const float* __restrict__ dinv, int* __restrict__ cur,
                          int2* __restrict__ ent) {
    int t = blockIdx.x * blockDim.x + threadIdx.x;
    if (t >= 2 * NE) return;
    int br = t >= NE;
    int e = t - br * NE;
    const int* S = br ? vei : ei;
    int s = S[e], d = S[NE + e];
    int pos = atomicAdd(&cur[br * NN + d], 1);
    int2 rec;
    rec.x = s;
    rec.y = __float_as_int(dinv[br * NN + s] * dinv[br * NN + d]);
    ent[br * NE + pos] = rec;
}

// Fused aggregate + layer-1 GEMM + epilogue (bias, relu, W2 dot) -> z.
// agg(X W) = agg(X) W: gather-aggregate bf16 xb rows (working set 25.6MB,
// half of old H) into a 64-node LDS tile, then MFMA with W1^T read straight
// from global (32KB/branch, L1-resident). H (51.2MB) is never materialized.
// Aggregation: half-wave per node (32 lanes x 4 feats), clamped 4-wide edge
// batches as before; ent has +8 rec padding.
__global__ __launch_bounds__(256) void k_agg_gemm(
        const ushort* __restrict__ xb, const ushort* __restrict__ Wcat,
        const float* __restrict__ dinv, const int* __restrict__ off,
        const int* __restrict__ cur, const int2* __restrict__ ent,
        const float* __restrict__ b1, const float* __restrict__ bv1,
        const float* __restrict__ W2, const float* __restrict__ Wv2,
        float* __restrict__ z) {
    __shared__ ushort As[64 * LDP];   // 17.4KB
    int bi = blockIdx.x;
    int br = bi >= NBAG;
    int n0 = (bi - br * NBAG) * 64;
    int tid = threadIdx.x;

    // ---- phase 1: aggregate 8 nodes per half-wave into As (bf16) ----
    {
        int hw = tid >> 5;
        int l = tid & 31;
        const int2* en = ent + br * NE;
        for (int nn = 0; nn < 8; ++nn) {
            int nl = hw * 8 + nn;
            int n = n0 + nl;
            uint2 pk = {0u, 0u};
            if (n < NN) {
                float dv = dinv[br * NN + n];
                uint2 u = *(const uint2*)(xb + (size_t)n * HD + l * 4);
                float c = dv * dv;
                float a0 = bf2f(u.x & 0xffffu) * c, a1 = bf2f(u.x >> 16) * c;
                float a2 = bf2f(u.y & 0xffffu) * c, a3 = bf2f(u.y >> 16) * c;
                int p0 = off[br * NN + n], p1 = cur[br * NN + n];
                for (int p = p0; p < p1; p += 4) {
                    int2 e0 = en[p], e1 = en[p + 1], e2 = en[p + 2], e3 = en[p + 3];
                    int s0 = e0.x;
                    int s1 = (p + 1 < p1) ? e1.x : n;
                    int s2 = (p + 2 < p1) ? e2.x : n;
                    int s3 = (p + 3 < p1) ? e3.x : n;
                    float c0 = __int_as_float(e0.y);
                    float c1 = (p + 1 < p1) ? __int_as_float(e1.y) : 0.f;
                    float c2 = (p + 2 < p1) ? __int_as_float(e2.y) : 0.f;
                    float c3 = (p + 3 < p1) ? __int_as_float(e3.y) : 0.f;
                    uint2 v0 = *(const uint2*)(xb + (size_t)s0 * HD + l * 4);
                    uint2 v1 = *(const uint2*)(xb + (size_t)s1 * HD + l * 4);
                    uint2 v2 = *(const uint2*)(xb + (size_t)s2 * HD + l * 4);
                    uint2 v3 = *(const uint2*)(xb + (size_t)s3 * HD + l * 4);
                    a0 += bf2f(v0.x & 0xffffu) * c0; a1 += bf2f(v0.x >> 16) * c0;
                    a2 += bf2f(v0.y & 0xffffu) * c0; a3 += bf2f(v0.y >> 16) * c0;
                    a0 += bf2f(v1.x & 0xffffu) * c1; a1 += bf2f(v1.x >> 16) * c1;
                    a2 += bf2f(v1.y & 0xffffu) * c1; a3 += bf2f(v1.y >> 16) * c1;
                    a0 += bf2f(v2.x & 0xffffu) * c2; a1 += bf2f(v2.x >> 16) * c2;
                    a2 += bf2f(v2.y & 0xffffu) * c2; a3 += bf2f(v2.y >> 16) * c2;
                    a0 += bf2f(v3.x & 0xffffu) * c3; a1 += bf2f(v3.x >> 16) * c3;
                    a2 += bf2f(v3.y & 0xffffu) * c3; a3 += bf2f(v3.y >> 16) * c3;
                }
                pk.x = (uint)f2bf(a0) | ((uint)f2bf(a1) << 16);
                pk.y = (uint)f2bf(a2) | ((uint)f2bf(a3) << 16);
            }
            *(uint2*)&As[nl * LDP + l * 4] = pk;
        }
    }
    __syncthreads();

    // ---- phase 2: [64 nodes] x W1 (128x128) with fused epilogue ----
    int w = tid >> 6, lane = tid & 63;
    int m = lane & 15, quad = lane >> 4;
    const ushort* Wg = Wcat + (size_t)br * 128 * 128;
    f32x4 acc[8] = {};
#pragma unroll
    for (int kc = 0; kc < 4; ++kc) {
        int k0 = kc * 32 + quad * 8;
        bf16x8 xf = *(const bf16x8*)&As[(w * 16 + m) * LDP + k0];
#pragma unroll
        for (int ft = 0; ft < 8; ++ft) {
            bf16x8 wf = *(const bf16x8*)&Wg[(ft * 16 + m) * 128 + k0];
            acc[ft] = __builtin_amdgcn_mfma_f32_16x16x32_bf16(wf, xf, acc[ft], 0, 0, 0);
        }
    }
    // lane holds feats f = ft*16 + quad*4 + j for node n0 + w*16 + m
    const float* bb = br ? bv1 : b1;
    const float* ww = br ? Wv2 : W2;
    float part = 0.f;
#pragma unroll
    for (int ft = 0; ft < 8; ++ft) {
        int f0 = ft * 16 + quad * 4;
        float4 b4 = *(const float4*)&bb[f0];
        float4 w4 = *(const float4*)&ww[f0];
        f32x4 a = acc[ft];
        part += fmaxf(a[0] + b4.x, 0.f) * w4.x + fmaxf(a[1] + b4.y, 0.f) * w4.y
              + fmaxf(a[2] + b4.z, 0.f) * w4.z + fmaxf(a[3] + b4.w, 0.f) * w4.w;
    }
    part += __shfl_xor(part, 16);
    part += __shfl_xor(part, 32);
    int n = n0 + w * 16 + m;
    if (quad == 0 && n < NN) z[br * NN + n] = part;
}

// Layer-2 aggregation + LDS-batched y reduction (batch is sorted).
// Clamped 4-wide z-walk for MLP.
__global__ void k_final2(const float* __restrict__ z, const float* __restrict__ dinv,
                         const int* __restrict__ off, const int* __restrict__ cur,
                         const int2* __restrict__ ent,
                         const float* __restrict__ b2, const float* __restrict__ bv2,
                         const int* __restrict__ batch, float* __restrict__ y) {
    __shared__ float ybuf[256];
    __shared__ int gbase_s;
    int br = blockIdx.x >= NB_SCAN;
    int nb = blockIdx.x - br * NB_SCAN;
    int tid = threadIdx.x;
    ybuf[tid] = 0.f;
    if (tid == 0) gbase_s = batch[nb * 256];
    __syncthreads();
    int gbase = gbase_s;
    int n = nb * 256 + tid;
    if (n < NN) {
        const int2* en = ent + br * NE;
        float dv = dinv[br * NN + n];
        float acc = z[br * NN + n] * dv * dv;
        int p1 = cur[br * NN + n];
        for (int p = off[br * NN + n]; p < p1; p += 4) {
            int2 e0 = en[p], e1 = en[p + 1], e2 = en[p + 2], e3 = en[p + 3];
            int s0 = e0.x;
            int s1 = (p + 1 < p1) ? e1.x : n;
            int s2 = (p + 2 < p1) ? e2.x : n;
            int s3 = (p + 3 < p1) ? e3.x : n;
            float c0 = __int_as_float(e0.y);
            float c1 = (p + 1 < p1) ? __int_as_float(e1.y) : 0.f;
            float c2 = (p + 2 < p1) ? __int_as_float(e2.y) : 0.f;
            float c3 = (p + 3 < p1) ? __int_as_float(e3.y) : 0.f;
            acc += c0 * z[br * NN + s0] + c1 * z[br * NN + s1]
                 + c2 * z[br * NN + s2] + c3 * z[br * NN + s3];
        }
        acc += br ? bv2[0] : b2[0];
        int gi = batch[n] - gbase;
        if (gi < 256) atomicAdd(&ybuf[gi], acc);
        else atomicAdd(&y[batch[n]], acc);
    }
    __syncthreads();
    float v = ybuf[tid];
    if (v != 0.f) atomicAdd(&y[gbase + tid], v);
}

extern "C" void kernel_launch(void* const* d_in, const int* in_sizes, int n_in,
                              void* d_out, int out_size, void* d_ws, size_t ws_size,
                              hipStream_t stream) {
    const int*   tok   = (const int*)d_in[0];
    const float* pe    = (const float*)d_in[1];
    const int*   ei    = (const int*)d_in[2];
    const int*   vei   = (const int*)d_in[3];
    const int*   batch = (const int*)d_in[4];
    const float* embed = (const float*)d_in[5];
    const float* Wtr   = (const float*)d_in[6];
    const float* bt    = (const float*)d_in[7];
    const float* W1    = (const float*)d_in[8];
    const float* b1    = (const float*)d_in[9];
    const float* W2    = (const float*)d_in[10];
    const float* b2    = (const float*)d_in[11];
    const float* Wv1   = (const float*)d_in[12];
    const float* bv1   = (const float*)d_in[13];
    const float* Wv2   = (const float*)d_in[14];
    const float* bv2   = (const float*)d_in[15];

    float* y = (float*)d_out;       // [NG]
    float* x = y + NG;              // [NN*HD], output 1

    char* w = (char*)d_ws;
    ushort* xb   = (ushort*)w;               w += (size_t)NN * HD * 2;
    ushort* Wcat = (ushort*)w;               w += 256 * 128 * 2;
    float*  dinv = (float*)w;                w += 2 * NN * 4;
    float*  z    = (float*)w;                w += 2 * NN * 4;
    int*    cnt  = (int*)w;                  w += 2 * NN * 4;
    int*    off  = (int*)w;                  w += 2 * NN * 4;
    int*    cur  = (int*)w;                  w += 2 * NN * 4;
    int2*   ent  = (int2*)w;                 w += (size_t)(2 * NE + 8) * 8;  // +8 pad
    int*    bsum = (int*)w;                  w += 2 * 512 * 4;

    hipMemsetAsync(y, 0, NG * sizeof(float), stream);
    hipMemsetAsync(cnt, 0, 2 * NN * sizeof(int), stream);

    k_front<<<NBX4 + NBW + NBD, 256, 0, stream>>>(tok, pe, embed, Wtr, bt, x, xb,
                                                  W1, Wv1, Wcat, ei, vei, cnt);
    k_scan1<<<2 * NB_SCAN, 256, 0, stream>>>(cnt, off, bsum, dinv);
    k_scan2<<<2, 512, 0, stream>>>(bsum);
    k_scan3<<<2 * NB_SCAN, 256, 0, stream>>>(off, bsum, cur);
    k_scatter<<<(2 * NE + 255) / 256, 256, 0, stream>>>(ei, vei, dinv, cur, ent);
    k_agg_gemm<<<2 * NBAG, 256, 0, stream>>>(xb, Wcat, dinv, off, cur, ent,
                                             b1, bv1, W2, Wv2, z);
    k_final2<<<2 * NB_SCAN, 256, 0, stream>>>(z, dinv, off, cur, ent,
                                              b2, bv2, batch, y);
}